// Round 8
// baseline (261.026 us; speedup 1.0000x reference)
//
#include <hip/hip_runtime.h>

// ViT cls-token-only forward. B=16, C=8, D=511, DIM=2048, SEQ=512, NH=16.
// q = (cls+pos0) @ Wq + bq; r[h] = SCALE * Wk_h @ q_h;
// scores[b,h,j] = tok[b,j].r[h]; softmax; u[b,h] = sum_j p tok[b,j];
// ao = u @ Wv + bv; out = ao @ proj_w + proj_b.
//
// R15 (resubmit; previous round was an infra failure, kernel never ran).
// k3 occupancy fix. R14's profile exposed k3: 60-62 µs with MfmaUtil 0.9%,
// VALU 3.8%, HBM 25%, Occupancy 18.5% -> latency-bound at 2 blocks/CU
// (traffic floor ~13 µs: x is L3-resident, FETCH=35MB).
//  - k3 ks-split 4 -> 8: grid 512 -> 1024 blocks = 4 blocks/CU (16 waves),
//    8 score-partial buffers; kk loop now 8 iters, FULLY unrolled so all
//    loads issue ahead of the convert->MFMA chain.
//  - k4 sums 8 partials.
//  - tok persistence kept (k5 reads 67 MB L3-hot instead of 201 MB).
//  - k1/k2/k5/k6/k7 unchanged from R14.

#define BB   16
#define CC   8
#define DD   511
#define DIM  2048
#define SEQ  512
#define NH   16
#define HD   128
#define W3   6144
#define SCALE 0.08838834764831845f

// workspace layout (float offsets)
#define QP_OFF   0            // 64*2048 q partials (plain)
#define G_OFF    131072       // 16 atomic gamma (zeroed by k1)
#define SCP_OFF  131088       // 8*131072 score partials (plain)
#define SCPSZ    131072
#define RB_OFF   1179664      // r bf16 hi/lo: 65536 shorts (32768 floats)
#define PF_OFF   1212432      // p fp32: 16b*16h*512 = 131072
#define UP_OFF   1343504      // u partials: 8 js * 16 b * 16 h * 2048 fp32
#define AOP_OFF  5537808      // ao partials: 32 ks * 16 b * 2048 fp32
#define TOKH_OFF 6586384      // tok hi: 16,777,216 shorts (8,388,608 floats)
#define TOKL_OFF 14974992     // tok lo: 16,777,216 shorts
// total = 23,363,600 floats ~= 93.5 MB

typedef __attribute__((ext_vector_type(8))) short short8;
typedef __attribute__((ext_vector_type(4))) float floatx4;
typedef __attribute__((ext_vector_type(2))) float floatx2;

static __device__ inline short bf_hi(float f) {
  return (short)(__float_as_uint(f) >> 16);          // truncate to bf16
}
static __device__ inline float bf_hif(float f) {
  return __uint_as_float(__float_as_uint(f) & 0xffff0000u);
}

// K1: q partials + zeroing. qpart[dc][n] = sum_{d in chunk} t0[d]*Wq[d][n]
// (+bias at dc==0). Zeroes gamma (16) and out (32768). grid (8 nt, 64 dc).
__global__ __launch_bounds__(256) void k1_q(
    const float* __restrict__ pos, const float* __restrict__ cls,
    const float* __restrict__ qkv_w, const float* __restrict__ qkv_b,
    float* __restrict__ ws, float* __restrict__ out) {
  int n  = blockIdx.x * 256 + threadIdx.x;
  int dc = blockIdx.y;
  int tid = (blockIdx.x + blockIdx.y * 8) * 256 + threadIdx.x;  // 0..131071
  if (tid < 16) ws[G_OFF + tid] = 0.f;
  if (tid < BB * DIM) out[tid] = 0.f;
  int d0 = dc * 32;
  float acc = (dc == 0) ? qkv_b[n] : 0.f;
#pragma unroll 8
  for (int d = d0; d < d0 + 32; ++d) {
    float t0 = cls[d] + pos[d];           // uniform -> scalar load
    acc += t0 * qkv_w[(size_t)d * W3 + n];
  }
  ws[QP_OFF + dc * DIM + n] = acc;
}

// K2: r[h][d] = SCALE * (Wk[d, h-slice] . q[h-slice]); q from summing the 64
// k1 partials. Writes bf16 hi/lo r + atomic gamma. grid (16 dtile, 16 h), 128.
__global__ __launch_bounds__(128) void k2_r(
    const float* __restrict__ qkv_w, const float* __restrict__ pos,
    const float* __restrict__ cls, float* __restrict__ ws) {
  __shared__ float qs[HD];
  int h = blockIdx.y;
  int d = blockIdx.x * 128 + threadIdx.x;
  float qa = 0.f;
#pragma unroll 8
  for (int c = 0; c < 64; ++c)
    qa += ws[QP_OFF + c * DIM + h * HD + threadIdx.x];
  qs[threadIdx.x] = qa;
  __syncthreads();
  const float4* w4 = reinterpret_cast<const float4*>(
      qkv_w + (size_t)d * W3 + DIM + h * HD);
  float acc = 0.f;
#pragma unroll 8
  for (int e4 = 0; e4 < 32; ++e4) {
    float4 w = w4[e4];
    acc += qs[e4*4+0]*w.x + qs[e4*4+1]*w.y + qs[e4*4+2]*w.z + qs[e4*4+3]*w.w;
  }
  float r = acc * SCALE;
  int i = h * DIM + d;
  short* rb = (short*)(ws + RB_OFF);
  rb[i] = bf_hi(r);
  rb[NH * DIM + i] = bf_hi(r - bf_hif(r));
  float g = (cls[d] + pos[d]) * r;        // fused gamma partial
  for (int m = 1; m < 64; m <<= 1) g += __shfl_xor(g, m, 64);
  if ((threadIdx.x & 63) == 0) atomicAdd(&ws[G_OFF + h], g);
}

// K3: scores[b,h,j>=1] via MFMA, 3-term hi/lo; also persists tok bf16 hi/lo
// to linear tok[b][j][d]. ks-split 8-way (8 kk each, fully unrolled);
// grid (8 jt2, 16 b, 8 ks), 256 thr = 4 waves -> 1024 blocks, 4/CU.
__global__ __launch_bounds__(256) void k3_scores_mfma(
    const float* __restrict__ x, const float* __restrict__ pos,
    float* __restrict__ ws) {
  int jt2 = blockIdx.x, b = blockIdx.y, ks = blockIdx.z;
  int t = threadIdx.x;
  int w = t >> 6, l = t & 63;
  int jt = jt2 * 4 + w;
  int m16 = l & 15, kg = l >> 4;
  int jrow = 1 + jt * 16 + m16;
  int jc = jrow < SEQ ? jrow : (SEQ - 1);   // clamp; jrow==512 masked at store
  const size_t xrow = (size_t)b * CC * DD * 256 + (size_t)(jc - 1) * 256;
  const short* rh = (const short*)(ws + RB_OFF);
  const short* rl = rh + NH * DIM;
  short* th = (short*)(ws + TOKH_OFF);
  short* tl = (short*)(ws + TOKL_OFF);
  const size_t trow = ((size_t)b * SEQ + jc) * DIM;
  floatx4 acc = {0.f, 0.f, 0.f, 0.f};
#pragma unroll
  for (int u = 0; u < 8; ++u) {
    int kk = ks * 8 + u;
    int d0 = kk * 32 + kg * 8;
    int c = d0 >> 8, doff = d0 & 255;
    const float4* xp = reinterpret_cast<const float4*>(
        x + xrow + (size_t)c * DD * 256 + doff);
    const float4* pp = reinterpret_cast<const float4*>(
        pos + (size_t)jc * DIM + d0);
    float4 xa = xp[0], xb = xp[1];
    float4 pa = pp[0], pb = pp[1];
    float f[8] = {xa.x + pa.x, xa.y + pa.y, xa.z + pa.z, xa.w + pa.w,
                  xb.x + pb.x, xb.y + pb.y, xb.z + pb.z, xb.w + pb.w};
    short8 ahi, alo;
#pragma unroll
    for (int i = 0; i < 8; ++i) {
      ahi[i] = bf_hi(f[i]);
      alo[i] = bf_hi(f[i] - bf_hif(f[i]));   // f-hi exact, then truncate
    }
    // persist tok fragments (j=511 written twice with identical bytes)
    *reinterpret_cast<short8*>(th + trow + d0) = ahi;
    *reinterpret_cast<short8*>(tl + trow + d0) = alo;
    short8 bhi = *reinterpret_cast<const short8*>(rh + m16 * DIM + d0);
    short8 blo = *reinterpret_cast<const short8*>(rl + m16 * DIM + d0);
    acc = __builtin_amdgcn_mfma_f32_16x16x32_bf16(ahi, bhi, acc, 0, 0, 0);
    acc = __builtin_amdgcn_mfma_f32_16x16x32_bf16(ahi, blo, acc, 0, 0, 0);
    acc = __builtin_amdgcn_mfma_f32_16x16x32_bf16(alo, bhi, acc, 0, 0, 0);
  }
  // C layout: col(h) = l&15, row(j) = (l>>4)*4 + reg  [m89-verified]
  int h = m16;
#pragma unroll
  for (int reg = 0; reg < 4; ++reg) {
    int row = kg * 4 + reg;
    int j = 1 + jt * 16 + row;
    if (j < SEQ)
      ws[SCP_OFF + (size_t)ks * SCPSZ + (size_t)(b * NH + h) * SEQ + j] =
          acc[reg];
  }
}

// K4: softmax per (b,h): sum 8 score partials + gamma -> p fp32.
// grid (16 h, 16 b) x 64 thr.
__global__ __launch_bounds__(64) void k4_softmax(float* __restrict__ ws) {
  int h = blockIdx.x, b = blockIdx.y, l = threadIdx.x;
  const float* sc0 = ws + SCP_OFF + (size_t)(b * NH + h) * SEQ;
  float gam = ws[G_OFF + h];
  float s[8];
#pragma unroll
  for (int i = 0; i < 8; ++i) {
    int j = i * 64 + l;
    float a = 0.f;
#pragma unroll
    for (int p = 0; p < 8; ++p) a += sc0[(size_t)p * SCPSZ + j];
    s[i] = a;
  }
  if (l == 0) s[0] = gam;                 // j=0 slot holds the cls score
  float mx = s[0];
#pragma unroll
  for (int i = 1; i < 8; ++i) mx = fmaxf(mx, s[i]);
  for (int m = 1; m < 64; m <<= 1) mx = fmaxf(mx, __shfl_xor(mx, m, 64));
  float e[8], sum = 0.f;
#pragma unroll
  for (int i = 0; i < 8; ++i) { e[i] = __expf(s[i] - mx); sum += e[i]; }
  for (int m = 1; m < 64; m <<= 1) sum += __shfl_xor(sum, m, 64);
  float inv = 1.f / sum;
  float* pf = ws + PF_OFF + (size_t)(b * NH + h) * SEQ;
#pragma unroll
  for (int i = 0; i < 8; ++i) pf[i * 64 + l] = e[i] * inv;
}

// K5: u (vector FMA) over persisted tok. Block (dt 0..3, b, js 0..7):
// d-range 512, j-range 64. Lane owns a d-pair: reads 4 B hi + 4 B lo
// (L3-hot, written by k3), reconstructs fp32 tok = hi + lo. p staged from
// PF to LDS, broadcast via uniform b128 reads. j=0 (cls row, not in tok)
// handled from cls+pos in js==0 blocks. grid (4 dt, 16 b, 8 js), 256 thr.
__global__ __launch_bounds__(256) void k5_pv(
    const float* __restrict__ pos, const float* __restrict__ cls,
    float* __restrict__ ws) {
  int dt = blockIdx.x, b = blockIdx.y, js = blockIdx.z, t = threadIdx.x;
  __shared__ __attribute__((aligned(16))) float pT[64][20];  // [j-local][h]
  for (int s = t; s < 1024; s += 256) {
    int h = s >> 6, jl = s & 63;
    pT[jl][h] = ws[PF_OFF + (size_t)(b * NH + h) * SEQ + js * 64 + jl];
  }
  __syncthreads();
  int d = dt * 512 + t * 2;
  const short* th = (const short*)(ws + TOKH_OFF);
  const short* tl = (const short*)(ws + TOKL_OFF);
  floatx2 acc[16];
#pragma unroll
  for (int h = 0; h < 16; ++h) acc[h] = (floatx2){0.f, 0.f};
  int jl0 = 0;
  if (js == 0) {                          // j=0: tok0 = cls + pos row 0
    floatx2 pv = *reinterpret_cast<const floatx2*>(pos + d);
    floatx2 cv = *reinterpret_cast<const floatx2*>(cls + d);
    floatx2 tok = cv + pv;
#pragma unroll
    for (int h4 = 0; h4 < 4; ++h4) {
      floatx4 p4 = *reinterpret_cast<const floatx4*>(&pT[0][h4 * 4]);
      acc[h4 * 4 + 0] += p4.x * tok;
      acc[h4 * 4 + 1] += p4.y * tok;
      acc[h4 * 4 + 2] += p4.z * tok;
      acc[h4 * 4 + 3] += p4.w * tok;
    }
    jl0 = 1;
  }
#pragma unroll 4
  for (int jl = jl0; jl < 64; ++jl) {
    int j = js * 64 + jl;
    size_t o = ((size_t)b * SEQ + j) * DIM + d;
    unsigned h2 = *reinterpret_cast<const unsigned*>(th + o);
    unsigned l2 = *reinterpret_cast<const unsigned*>(tl + o);
    floatx2 tok;
    tok.x = __uint_as_float((h2 & 0xffffu) << 16) +
            __uint_as_float((l2 & 0xffffu) << 16);
    tok.y = __uint_as_float(h2 & 0xffff0000u) +
            __uint_as_float(l2 & 0xffff0000u);
#pragma unroll
    for (int h4 = 0; h4 < 4; ++h4) {
      floatx4 p4 = *reinterpret_cast<const floatx4*>(&pT[jl][h4 * 4]);
      acc[h4 * 4 + 0] += p4.x * tok;
      acc[h4 * 4 + 1] += p4.y * tok;
      acc[h4 * 4 + 2] += p4.z * tok;
      acc[h4 * 4 + 3] += p4.w * tok;
    }
  }
  float* ub = ws + UP_OFF + (size_t)(js * 16 + b) * 16 * 2048 + d;
#pragma unroll
  for (int h = 0; h < 16; ++h)
    *reinterpret_cast<floatx2*>(ub + (size_t)h * 2048) = acc[h];
}

// K6: ao partials. Block (nt, ks 0..31): m-range 256 (heads nt*2, nt*2+1),
// d-range 64. Stage u (summing 8 js-partials) to LDS [hh][dd][b]; loop dd:
// coalesced Wv column load + 16 FMA via uniform b128 broadcast. Plain store
// aop[ks][b][m]. grid (8 nt, 32 ks), 256 thr.
__global__ __launch_bounds__(256) void k6_ao(
    const float* __restrict__ qkv_w, const float* __restrict__ qkv_b,
    float* __restrict__ ws) {
  int nt = blockIdx.x, ks = blockIdx.y, t = threadIdx.x;
  int m = nt * 256 + t;
  int h0 = nt * 2;
  __shared__ __attribute__((aligned(16))) float us[2][64][20];
  for (int s = t; s < 2048; s += 256) {
    int dd = s & 63, bb = (s >> 6) & 15, hh = s >> 10;
    float a = 0.f;
#pragma unroll
    for (int js = 0; js < 8; ++js)
      a += ws[UP_OFF + (size_t)(js * 16 + bb) * 16 * 2048 +
              (size_t)(h0 + hh) * 2048 + ks * 64 + dd];
    us[hh][dd][bb] = a;
  }
  __syncthreads();
  int hl = t >> 7;
  float acc[BB];
#pragma unroll
  for (int bb = 0; bb < BB; ++bb) acc[bb] = 0.f;
  const float* wcol = qkv_w + (size_t)(ks * 64) * W3 + 2 * DIM + m;
#pragma unroll 4
  for (int dd = 0; dd < 64; ++dd) {
    float wv = wcol[(size_t)dd * W3];
    floatx4 u0 = *reinterpret_cast<const floatx4*>(&us[hl][dd][0]);
    floatx4 u1 = *reinterpret_cast<const floatx4*>(&us[hl][dd][4]);
    floatx4 u2 = *reinterpret_cast<const floatx4*>(&us[hl][dd][8]);
    floatx4 u3 = *reinterpret_cast<const floatx4*>(&us[hl][dd][12]);
    acc[0]  += u0.x * wv; acc[1]  += u0.y * wv; acc[2]  += u0.z * wv; acc[3]  += u0.w * wv;
    acc[4]  += u1.x * wv; acc[5]  += u1.y * wv; acc[6]  += u1.z * wv; acc[7]  += u1.w * wv;
    acc[8]  += u2.x * wv; acc[9]  += u2.y * wv; acc[10] += u2.z * wv; acc[11] += u2.w * wv;
    acc[12] += u3.x * wv; acc[13] += u3.y * wv; acc[14] += u3.z * wv; acc[15] += u3.w * wv;
  }
  float bias = (ks == 0) ? qkv_b[2 * DIM + m] : 0.f;
#pragma unroll
  for (int bb = 0; bb < BB; ++bb)
    ws[AOP_OFF + (size_t)(ks * 16 + bb) * 2048 + m] = acc[bb] + bias;
}

// K7: out. Block (nt, ms 0..31): n-range 256, m-range 64. Stage ao (summing
// 32 ks-partials) to LDS [mm][b]; loop mm: coalesced proj load + 16 FMA via
// uniform b128 broadcast; atomicAdd into out (zeroed by k1).
// grid (8 nt, 32 ms), 256 thr.
__global__ __launch_bounds__(256) void k7_out(
    const float* __restrict__ proj_w, const float* __restrict__ proj_b,
    const float* __restrict__ ws, float* __restrict__ out) {
  int nt = blockIdx.x, ms = blockIdx.y, t = threadIdx.x;
  int n = nt * 256 + t;
  int m0 = ms * 64;
  __shared__ __attribute__((aligned(16))) float as[64][20];
  for (int s = t; s < 1024; s += 256) {
    int mm = s & 63, bb = s >> 6;
    float a = 0.f;
#pragma unroll
    for (int ks = 0; ks < 32; ++ks)
      a += ws[AOP_OFF + (size_t)(ks * 16 + bb) * 2048 + m0 + mm];
    as[mm][bb] = a;
  }
  __syncthreads();
  float acc[BB];
#pragma unroll
  for (int bb = 0; bb < BB; ++bb) acc[bb] = 0.f;
  const float* wcol = proj_w + (size_t)m0 * DIM + n;
#pragma unroll 4
  for (int mm = 0; mm < 64; ++mm) {
    float wv = wcol[(size_t)mm * DIM];
    floatx4 a0 = *reinterpret_cast<const floatx4*>(&as[mm][0]);
    floatx4 a1 = *reinterpret_cast<const floatx4*>(&as[mm][4]);
    floatx4 a2 = *reinterpret_cast<const floatx4*>(&as[mm][8]);
    floatx4 a3 = *reinterpret_cast<const floatx4*>(&as[mm][12]);
    acc[0]  += a0.x * wv; acc[1]  += a0.y * wv; acc[2]  += a0.z * wv; acc[3]  += a0.w * wv;
    acc[4]  += a1.x * wv; acc[5]  += a1.y * wv; acc[6]  += a1.z * wv; acc[7]  += a1.w * wv;
    acc[8]  += a2.x * wv; acc[9]  += a2.y * wv; acc[10] += a2.z * wv; acc[11] += a2.w * wv;
    acc[12] += a3.x * wv; acc[13] += a3.y * wv; acc[14] += a3.z * wv; acc[15] += a3.w * wv;
  }
  float bias = (ms == 0) ? proj_b[n] : 0.f;
#pragma unroll
  for (int bb = 0; bb < BB; ++bb)
    atomicAdd(&out[bb * DIM + n], acc[bb] + bias);
}

extern "C" void kernel_launch(void* const* d_in, const int* in_sizes, int n_in,
                              void* d_out, int out_size, void* d_ws, size_t ws_size,
                              hipStream_t stream) {
  const float* x      = (const float*)d_in[0];
  const float* pos    = (const float*)d_in[1];
  const float* cls    = (const float*)d_in[2];
  const float* qkv_w  = (const float*)d_in[3];
  const float* qkv_b  = (const float*)d_in[4];
  const float* proj_w = (const float*)d_in[5];
  const float* proj_b = (const float*)d_in[6];
  float* ws  = (float*)d_ws;
  float* out = (float*)d_out;

  k1_q          <<<dim3(8, 64),    256, 0, stream>>>(pos, cls, qkv_w, qkv_b, ws, out);
  k2_r          <<<dim3(16, 16),   128, 0, stream>>>(qkv_w, pos, cls, ws);
  k3_scores_mfma<<<dim3(8, 16, 8), 256, 0, stream>>>(x, pos, ws);
  k4_softmax    <<<dim3(16, 16),    64, 0, stream>>>(ws);
  k5_pv         <<<dim3(4, 16, 8), 256, 0, stream>>>(pos, cls, ws);
  k6_ao         <<<dim3(8, 32),    256, 0, stream>>>(qkv_w, qkv_b, ws);
  k7_out        <<<dim3(8, 32),    256, 0, stream>>>(proj_w, proj_b, ws, out);
}

// Round 9
// 219.791 us; speedup vs baseline: 1.1876x; 1.1876x over previous
//
#include <hip/hip_runtime.h>

// ViT cls-token-only forward. B=16, C=8, D=511, DIM=2048, SEQ=512, NH=16.
// q = (cls+pos0) @ Wq + bq; r[h] = SCALE * Wk_h @ q_h;
// scores[b,h,j] = tok[b,j].r[h]; softmax; u[b,h] = sum_j p tok[b,j];
// ao = u @ Wv + bv; out = ao @ proj_w + proj_b.
//
// R16: return to the R9 structure (221.5 µs verified; k1/k2/k5-PV/k6/k7
// byte-identical) + one well-understood change from the R15 evidence:
//  - k3 was 62 µs at 1.96 TB/s (31% of achievable), invariant to occupancy
//    doubling -> HBM request-efficiency bound (16-B scattered pieces).
//    Rewritten: 64j x 128d tile staged to LDS with perfectly coalesced
//    512-B-contiguous x/pos reads, bf16 hi/lo built once in LDS, fragments
//    via aligned ds_read_b128 (row stride 272 B -> <=2-way banks). Writes
//    16 plain per-d-chunk score partials (no atomics). Tok-store reverted.
//  - new k4: softmax once per (b,h) over the 16 partials + gamma -> p in
//    bf16 hi/lo (bitwise-identical p math to R9's fused version).
//  - k5: softmax phase replaced by tiny PB->LDS copy (kills the 32x
//    redundant SCP re-read, ~67 MB L2/L3); PV core verbatim R9.

#define BB   16
#define CC   8
#define DD   511
#define DIM  2048
#define SEQ  512
#define NH   16
#define HD   128
#define W3   6144
#define SCALE 0.08838834764831845f

// workspace layout (float offsets)
#define QP_OFF   0            // 64*2048 q partials (plain)
#define G_OFF    131072       // 16 atomic gamma (zeroed by k1)
#define AO_OFF   131088       // 32768 atomic ao (zeroed by k1, G+AO contig)
#define SCP_OFF  163856       // 16*131072 score partials (plain)
#define SCPSZ    131072
#define RB_OFF   2261008      // r bf16 hi/lo: 65536 shorts (32768 floats)
#define PB_OFF   2293776      // p bf16 hi/lo: 262144 shorts (131072 floats)
#define U_OFF    2424848      // 524288 u fp32
// total = 2,949,136 floats ~= 11.8 MB

#define PSTR 520
#define CJ   32               // k5 j-chunk rows
#define TSTR 68               // k5 tok LDS short-stride

typedef __attribute__((ext_vector_type(8))) short short8;
typedef __attribute__((ext_vector_type(4))) float floatx4;

static __device__ inline short bf_hi(float f) {
  return (short)(__float_as_uint(f) >> 16);          // truncate to bf16
}
static __device__ inline float bf_hif(float f) {
  return __uint_as_float(__float_as_uint(f) & 0xffff0000u);
}

// K1: q partials + zeroing (verbatim R9). grid (8 nt, 64 dc) x 256.
__global__ __launch_bounds__(256) void k1_q(
    const float* __restrict__ pos, const float* __restrict__ cls,
    const float* __restrict__ qkv_w, const float* __restrict__ qkv_b,
    float* __restrict__ ws, float* __restrict__ out) {
  int n  = blockIdx.x * 256 + threadIdx.x;
  int dc = blockIdx.y;
  int tid = (blockIdx.x + blockIdx.y * 8) * 256 + threadIdx.x;  // 0..131071
  if (tid < 32784) ws[G_OFF + tid] = 0.f;        // G + AO contiguous
  if (tid < BB * DIM) out[tid] = 0.f;
  int d0 = dc * 32;
  float acc = (dc == 0) ? qkv_b[n] : 0.f;
#pragma unroll 8
  for (int d = d0; d < d0 + 32; ++d) {
    float t0 = cls[d] + pos[d];           // uniform -> scalar load
    acc += t0 * qkv_w[(size_t)d * W3 + n];
  }
  ws[QP_OFF + dc * DIM + n] = acc;
}

// K2: r[h][d] (verbatim R9). grid (16 dtile, 16 h), 128 thr.
__global__ __launch_bounds__(128) void k2_r(
    const float* __restrict__ qkv_w, const float* __restrict__ pos,
    const float* __restrict__ cls, float* __restrict__ ws) {
  __shared__ float qs[HD];
  int h = blockIdx.y;
  int d = blockIdx.x * 128 + threadIdx.x;
  float qa = 0.f;
#pragma unroll 8
  for (int c = 0; c < 64; ++c)
    qa += ws[QP_OFF + c * DIM + h * HD + threadIdx.x];
  qs[threadIdx.x] = qa;
  __syncthreads();
  const float4* w4 = reinterpret_cast<const float4*>(
      qkv_w + (size_t)d * W3 + DIM + h * HD);
  float acc = 0.f;
#pragma unroll 8
  for (int e4 = 0; e4 < 32; ++e4) {
    float4 w = w4[e4];
    acc += qs[e4*4+0]*w.x + qs[e4*4+1]*w.y + qs[e4*4+2]*w.z + qs[e4*4+3]*w.w;
  }
  float r = acc * SCALE;
  int i = h * DIM + d;
  short* rb = (short*)(ws + RB_OFF);
  rb[i] = bf_hi(r);
  rb[NH * DIM + i] = bf_hi(r - bf_hif(r));
  float g = (cls[d] + pos[d]) * r;
  for (int m = 1; m < 64; m <<= 1) g += __shfl_xor(g, m, 64);
  if ((threadIdx.x & 63) == 0) atomicAdd(&ws[G_OFF + h], g);
}

// K3: scores via MFMA with LDS-staged coalesced tok tile. Block (jt,b,dc):
// 64 j x 128 d. Stage: 2048 float4 of x + pos (512-B contiguous runs/wave),
// bf16 hi/lo in LDS (rows 136 shorts = 272 B -> 16-B aligned, <=2-way bank).
// Wave w does j-subtile w*16..w*16+15; 4 kk x 3 MFMA; plain store into the
// dc-th score partial. grid (8 jt, 16 b, 16 dc), 256 thr.
__global__ __launch_bounds__(256) void k3_scores_mfma(
    const float* __restrict__ x, const float* __restrict__ pos,
    float* __restrict__ ws) {
  int jt = blockIdx.x, b = blockIdx.y, dc = blockIdx.z;
  int t = threadIdx.x;
  __shared__ __attribute__((aligned(16))) short ths[64][136];
  __shared__ __attribute__((aligned(16))) short tls[64][136];
  const size_t xb = (size_t)b * CC * DD * 256;
#pragma unroll
  for (int i = 0; i < 8; ++i) {
    int idx = i * 256 + t;                // 0..2047
    int r = idx >> 5;                     // row 0..63
    int c4 = idx & 31;                    // float4 within row
    int jr = 1 + jt * 64 + r;
    if (jr > 511) jr = 511;               // clamp (dup row, masked at store)
    int d = dc * 128 + c4 * 4;
    int cc = d >> 8, doff = d & 255;
    float4 xv = *reinterpret_cast<const float4*>(
        x + xb + (size_t)cc * DD * 256 + (size_t)(jr - 1) * 256 + doff);
    float4 pv = *reinterpret_cast<const float4*>(pos + (size_t)jr * DIM + d);
    float f[4] = {xv.x + pv.x, xv.y + pv.y, xv.z + pv.z, xv.w + pv.w};
#pragma unroll
    for (int k = 0; k < 4; ++k) {
      ths[r][c4 * 4 + k] = bf_hi(f[k]);
      tls[r][c4 * 4 + k] = bf_hi(f[k] - bf_hif(f[k]));
    }
  }
  __syncthreads();
  int w = t >> 6, l = t & 63;
  int m16 = l & 15, kg = l >> 4;
  const short* rh = (const short*)(ws + RB_OFF);
  const short* rl = rh + NH * DIM;
  floatx4 acc = {0.f, 0.f, 0.f, 0.f};
#pragma unroll
  for (int kk = 0; kk < 4; ++kk) {
    int dl = kk * 32 + kg * 8;            // local d 0..127
    int gd = dc * 128 + dl;               // global d
    short8 ahi = *reinterpret_cast<const short8*>(&ths[w * 16 + m16][dl]);
    short8 alo = *reinterpret_cast<const short8*>(&tls[w * 16 + m16][dl]);
    short8 bhi = *reinterpret_cast<const short8*>(rh + m16 * DIM + gd);
    short8 blo = *reinterpret_cast<const short8*>(rl + m16 * DIM + gd);
    acc = __builtin_amdgcn_mfma_f32_16x16x32_bf16(ahi, bhi, acc, 0, 0, 0);
    acc = __builtin_amdgcn_mfma_f32_16x16x32_bf16(ahi, blo, acc, 0, 0, 0);
    acc = __builtin_amdgcn_mfma_f32_16x16x32_bf16(alo, bhi, acc, 0, 0, 0);
  }
  // C layout: col(h) = l&15, row(j) = kg*4 + reg  [m89-verified]
  int h = m16;
#pragma unroll
  for (int reg = 0; reg < 4; ++reg) {
    int j = 1 + jt * 64 + w * 16 + kg * 4 + reg;
    if (j < SEQ)
      ws[SCP_OFF + (size_t)dc * SCPSZ + (size_t)(b * NH + h) * SEQ + j] =
          acc[reg];
  }
}

// K4: softmax per (b,h): sum 16 score partials + gamma -> p bf16 hi/lo
// (bitwise-identical p math to R9's fused softmax). grid (16 h, 16 b) x 64.
__global__ __launch_bounds__(64) void k4_softmax(float* __restrict__ ws) {
  int h = blockIdx.x, b = blockIdx.y, l = threadIdx.x;
  const float* sc0 = ws + SCP_OFF + (size_t)(b * NH + h) * SEQ;
  float gam = ws[G_OFF + h];
  float s[8];
#pragma unroll
  for (int i = 0; i < 8; ++i) {
    int j = i * 64 + l;
    float a = 0.f;
#pragma unroll
    for (int p = 0; p < 16; ++p) a += sc0[(size_t)p * SCPSZ + j];
    s[i] = a;
  }
  if (l == 0) s[0] = gam;                 // j=0 slot holds the cls score
  float mx = s[0];
#pragma unroll
  for (int i = 1; i < 8; ++i) mx = fmaxf(mx, s[i]);
  for (int m = 1; m < 64; m <<= 1) mx = fmaxf(mx, __shfl_xor(mx, m, 64));
  float e[8], sum = 0.f;
#pragma unroll
  for (int i = 0; i < 8; ++i) { e[i] = __expf(s[i] - mx); sum += e[i]; }
  for (int m = 1; m < 64; m <<= 1) sum += __shfl_xor(sum, m, 64);
  float inv = 1.f / sum;
  short* ph = (short*)(ws + PB_OFF);
  short* pl = ph + NH * SEQ * BB;
#pragma unroll
  for (int i = 0; i < 8; ++i) {
    float p = e[i] * inv;
    int j = i * 64 + l;
    ph[(size_t)(b * NH + h) * SEQ + j] = bf_hi(p);
    pl[(size_t)(b * NH + h) * SEQ + j] = bf_hi(p - bf_hif(p));
  }
}

// K5: u[b] = p @ tok via MFMA (PV core verbatim R9; softmax phase replaced
// by PB->LDS copy). grid (32 dt, 16 b), 256 thr.
__global__ __launch_bounds__(256) void k5_pv_mfma(
    const float* __restrict__ x, const float* __restrict__ pos,
    const float* __restrict__ cls, float* __restrict__ ws) {
  int dt = blockIdx.x, b = blockIdx.y, t = threadIdx.x;
  __shared__ __attribute__((aligned(16))) short phl[NH * PSTR];
  __shared__ __attribute__((aligned(16))) short pll[NH * PSTR];
  __shared__ short ths[2][CJ][TSTR];
  __shared__ short tls[2][CJ][TSTR];
  int w = t >> 6, l = t & 63;
  // ---- p staging from PB (tiny; replaces the fused softmax) ----
  const short* phg = (const short*)(ws + PB_OFF);
  const short* plg = phg + NH * SEQ * BB;
  for (int s = t; s < NH * SEQ / 2; s += 256) {
    int h = s >> 8, j2 = (s & 255) * 2;
    *reinterpret_cast<int*>(&phl[h * PSTR + j2]) =
        *reinterpret_cast<const int*>(&phg[(size_t)(b * NH + h) * SEQ + j2]);
    *reinterpret_cast<int*>(&pll[h * PSTR + j2]) =
        *reinterpret_cast<const int*>(&plg[(size_t)(b * NH + h) * SEQ + j2]);
  }
  // ---- tok staging: 32j x 64d chunk, coalesced float4, bf16 hi/lo ----
  const size_t xb = (size_t)b * CC * DD * 256;
  auto stage = [&](int kk, int buf) {
#pragma unroll
    for (int rep = 0; rep < 2; ++rep) {
      int idx = rep * 256 + t;
      int jj = idx >> 4, f4 = idx & 15;   // 32 rows x 16 float4
      int j = kk * CJ + jj;
      int dbase = dt * 64 + f4 * 4;
      float4 pv = *reinterpret_cast<const float4*>(pos + (size_t)j * DIM + dbase);
      float4 xv;
      if (j == 0) {
        xv = *reinterpret_cast<const float4*>(cls + dbase);
      } else {
        int c = dbase >> 8, doff = dbase & 255;
        xv = *reinterpret_cast<const float4*>(
            x + xb + (size_t)c * DD * 256 + (size_t)(j - 1) * 256 + doff);
      }
      float f[4] = {xv.x + pv.x, xv.y + pv.y, xv.z + pv.z, xv.w + pv.w};
#pragma unroll
      for (int k = 0; k < 4; ++k) {
        ths[buf][jj][f4 * 4 + k] = bf_hi(f[k]);
        tls[buf][jj][f4 * 4 + k] = bf_hi(f[k] - bf_hif(f[k]));
      }
    }
  };
  stage(0, 0);
  // ---- MFMA main loop (double-buffered over 16 j-chunks) ----
  int m16 = l & 15, kq = l >> 4;
  int wd = w * 16 + m16;
  int dcol = dt * 64 + wd;
  const short8* pph = reinterpret_cast<const short8*>(&phl[m16 * PSTR]);
  const short8* ppl = reinterpret_cast<const short8*>(&pll[m16 * PSTR]);
  floatx4 acc = {0.f, 0.f, 0.f, 0.f};
  for (int kk = 0; kk < 16; ++kk) {
    __syncthreads();
    if (kk < 15) stage(kk + 1, (kk + 1) & 1);
    int buf = kk & 1;
    short8 thi, tlo;
#pragma unroll
    for (int i = 0; i < 8; ++i) {
      thi[i] = ths[buf][kq * 8 + i][wd];
      tlo[i] = tls[buf][kq * 8 + i][wd];
    }
    short8 phi = pph[kk * 4 + kq];
    short8 plo = ppl[kk * 4 + kq];
    acc = __builtin_amdgcn_mfma_f32_16x16x32_bf16(phi, thi, acc, 0, 0, 0);
    acc = __builtin_amdgcn_mfma_f32_16x16x32_bf16(phi, tlo, acc, 0, 0, 0);
    acc = __builtin_amdgcn_mfma_f32_16x16x32_bf16(plo, thi, acc, 0, 0, 0);
  }
  // C: col(d) = l&15, row(h) = kq*4+reg
  float* ub = ws + U_OFF + (size_t)b * NH * DIM + dcol;
#pragma unroll
  for (int reg = 0; reg < 4; ++reg)
    ub[(size_t)(kq * 4 + reg) * DIM] = acc[reg];
}

// K6: ao[b][m] += u-chunk . Wv (verbatim R9). grid (8 nt, 64 dc).
__global__ __launch_bounds__(256) void k6_ao(
    const float* __restrict__ qkv_w, const float* __restrict__ qkv_b,
    float* __restrict__ ws) {
  int nt = blockIdx.x, dc = blockIdx.y, t = threadIdx.x;
  int m = nt * 256 + t;
  int h0 = nt * 2;
  int d0 = dc * 32;
  __shared__ float us[2][32][20];
  for (int i = t; i < 2 * 32 * BB; i += 256) {
    int dd = i & 31, b = (i >> 5) & 15, hh = i >> 9;
    us[hh][dd][b] = ws[U_OFF + (size_t)(b * NH + h0 + hh) * DIM + d0 + dd];
  }
  __syncthreads();
  int hl = t >> 7;
  float acc[BB];
#pragma unroll
  for (int b = 0; b < BB; ++b) acc[b] = 0.f;
  const float* wcol = qkv_w + (size_t)d0 * W3 + 2 * DIM + m;
#pragma unroll 4
  for (int dd = 0; dd < 32; ++dd) {
    float w = wcol[(size_t)dd * W3];
    const float4* u4 = reinterpret_cast<const float4*>(&us[hl][dd][0]);
    float4 u0 = u4[0], u1 = u4[1], u2 = u4[2], u3 = u4[3];
    acc[0]  += u0.x * w; acc[1]  += u0.y * w; acc[2]  += u0.z * w; acc[3]  += u0.w * w;
    acc[4]  += u1.x * w; acc[5]  += u1.y * w; acc[6]  += u1.z * w; acc[7]  += u1.w * w;
    acc[8]  += u2.x * w; acc[9]  += u2.y * w; acc[10] += u2.z * w; acc[11] += u2.w * w;
    acc[12] += u3.x * w; acc[13] += u3.y * w; acc[14] += u3.z * w; acc[15] += u3.w * w;
  }
  float bias = (dc == 0) ? qkv_b[2 * DIM + m] : 0.f;
#pragma unroll
  for (int b = 0; b < BB; ++b)
    atomicAdd(&ws[AO_OFF + b * DIM + m], acc[b] + bias);
}

// K7: out[b][n] += ao-chunk . proj_w (verbatim R9). grid (8 nt, 64 mc).
__global__ __launch_bounds__(256) void k7_out(
    const float* __restrict__ proj_w, const float* __restrict__ proj_b,
    const float* __restrict__ ws, float* __restrict__ out) {
  int nt = blockIdx.x, mc = blockIdx.y, t = threadIdx.x;
  int n = nt * 256 + t;
  int m0 = mc * 32;
  __shared__ float as[32][20];
  for (int i = t; i < 32 * BB; i += 256) {
    int mm = i & 31, b = i >> 5;
    as[mm][b] = ws[AO_OFF + b * DIM + m0 + mm];
  }
  __syncthreads();
  float acc[BB];
#pragma unroll
  for (int b = 0; b < BB; ++b) acc[b] = 0.f;
  const float* wcol = proj_w + (size_t)m0 * DIM + n;
#pragma unroll 4
  for (int mm = 0; mm < 32; ++mm) {
    float w = wcol[(size_t)mm * DIM];
    const float4* a4 = reinterpret_cast<const float4*>(&as[mm][0]);
    float4 a0 = a4[0], a1 = a4[1], a2 = a4[2], a3 = a4[3];
    acc[0]  += a0.x * w; acc[1]  += a0.y * w; acc[2]  += a0.z * w; acc[3]  += a0.w * w;
    acc[4]  += a1.x * w; acc[5]  += a1.y * w; acc[6]  += a1.z * w; acc[7]  += a1.w * w;
    acc[8]  += a2.x * w; acc[9]  += a2.y * w; acc[10] += a2.z * w; acc[11] += a2.w * w;
    acc[12] += a3.x * w; acc[13] += a3.y * w; acc[14] += a3.z * w; acc[15] += a3.w * w;
  }
  float bias = (mc == 0) ? proj_b[n] : 0.f;
#pragma unroll
  for (int b = 0; b < BB; ++b)
    atomicAdd(&out[b * DIM + n], acc[b] + bias);
}

extern "C" void kernel_launch(void* const* d_in, const int* in_sizes, int n_in,
                              void* d_out, int out_size, void* d_ws, size_t ws_size,
                              hipStream_t stream) {
  const float* x      = (const float*)d_in[0];
  const float* pos    = (const float*)d_in[1];
  const float* cls    = (const float*)d_in[2];
  const float* qkv_w  = (const float*)d_in[3];
  const float* qkv_b  = (const float*)d_in[4];
  const float* proj_w = (const float*)d_in[5];
  const float* proj_b = (const float*)d_in[6];
  float* ws  = (float*)d_ws;
  float* out = (float*)d_out;

  k1_q          <<<dim3(8, 64),     256, 0, stream>>>(pos, cls, qkv_w, qkv_b, ws, out);
  k2_r          <<<dim3(16, 16),    128, 0, stream>>>(qkv_w, pos, cls, ws);
  k3_scores_mfma<<<dim3(8, 16, 16), 256, 0, stream>>>(x, pos, ws);
  k4_softmax    <<<dim3(16, 16),     64, 0, stream>>>(ws);
  k5_pv_mfma    <<<dim3(32, 16),    256, 0, stream>>>(x, pos, cls, ws);
  k6_ao         <<<dim3(8, 64),     256, 0, stream>>>(qkv_w, qkv_b, ws);
  k7_out        <<<dim3(8, 64),     256, 0, stream>>>(proj_w, proj_b, ws, out);
}

// Round 10
// 218.836 us; speedup vs baseline: 1.1928x; 1.0044x over previous
//
#include <hip/hip_runtime.h>

// ViT cls-token-only forward. B=16, C=8, D=511, DIM=2048, SEQ=512, NH=16.
// q = (cls+pos0) @ Wq + bq; r[h] = SCALE * Wk_h @ q_h;
// scores[b,h,j] = tok[b,j].r[h]; softmax; u[b,h] = sum_j p tok[b,j];
// ao = u @ Wv + bv; out = ao @ proj_w + proj_b.
//
// R17: k5 barrier/occupancy fix (one change vs R16's 219.8 µs best).
// R16 evidence: k3's 62->~30 µs came from fixing latency exposure; k5 has
// the same staging structure but 16 __syncthreads()/block at 2 blocks/CU.
//  - k5 split 2-way over j (js in {0,1}): 1024 blocks = 4/CU (halved p-LDS),
//    8 barriers/block, each block stages its 256-j half and writes a
//    u-partial. Per-element math identical; u = partial0 + partial1.
//  - k6 sums the 2 u-partials during its existing LDS staging.
//  - k1/k2/k3/k4/k7 byte-identical to R16.

#define BB   16
#define CC   8
#define DD   511
#define DIM  2048
#define SEQ  512
#define NH   16
#define HD   128
#define W3   6144
#define SCALE 0.08838834764831845f

// workspace layout (float offsets)
#define QP_OFF   0            // 64*2048 q partials (plain)
#define G_OFF    131072       // 16 atomic gamma (zeroed by k1)
#define AO_OFF   131088       // 32768 atomic ao (zeroed by k1, G+AO contig)
#define SCP_OFF  163856       // 16*131072 score partials (plain)
#define SCPSZ    131072
#define RB_OFF   2261008      // r bf16 hi/lo: 65536 shorts (32768 floats)
#define PB_OFF   2293776      // p bf16 hi/lo: 262144 shorts (131072 floats)
#define U_OFF    2424848      // 2 js * 524288 u partials (plain)
#define USZ      524288
// total = 3,473,424 floats ~= 13.9 MB

#define PSTR 264              // k5 p-LDS row stride (256 j-half + pad)
#define CJ   32               // k5 j-chunk rows
#define TSTR 68               // k5 tok LDS short-stride

typedef __attribute__((ext_vector_type(8))) short short8;
typedef __attribute__((ext_vector_type(4))) float floatx4;

static __device__ inline short bf_hi(float f) {
  return (short)(__float_as_uint(f) >> 16);          // truncate to bf16
}
static __device__ inline float bf_hif(float f) {
  return __uint_as_float(__float_as_uint(f) & 0xffff0000u);
}

// K1: q partials + zeroing (verbatim R16). grid (8 nt, 64 dc) x 256.
__global__ __launch_bounds__(256) void k1_q(
    const float* __restrict__ pos, const float* __restrict__ cls,
    const float* __restrict__ qkv_w, const float* __restrict__ qkv_b,
    float* __restrict__ ws, float* __restrict__ out) {
  int n  = blockIdx.x * 256 + threadIdx.x;
  int dc = blockIdx.y;
  int tid = (blockIdx.x + blockIdx.y * 8) * 256 + threadIdx.x;  // 0..131071
  if (tid < 32784) ws[G_OFF + tid] = 0.f;        // G + AO contiguous
  if (tid < BB * DIM) out[tid] = 0.f;
  int d0 = dc * 32;
  float acc = (dc == 0) ? qkv_b[n] : 0.f;
#pragma unroll 8
  for (int d = d0; d < d0 + 32; ++d) {
    float t0 = cls[d] + pos[d];           // uniform -> scalar load
    acc += t0 * qkv_w[(size_t)d * W3 + n];
  }
  ws[QP_OFF + dc * DIM + n] = acc;
}

// K2: r[h][d] (verbatim R16). grid (16 dtile, 16 h), 128 thr.
__global__ __launch_bounds__(128) void k2_r(
    const float* __restrict__ qkv_w, const float* __restrict__ pos,
    const float* __restrict__ cls, float* __restrict__ ws) {
  __shared__ float qs[HD];
  int h = blockIdx.y;
  int d = blockIdx.x * 128 + threadIdx.x;
  float qa = 0.f;
#pragma unroll 8
  for (int c = 0; c < 64; ++c)
    qa += ws[QP_OFF + c * DIM + h * HD + threadIdx.x];
  qs[threadIdx.x] = qa;
  __syncthreads();
  const float4* w4 = reinterpret_cast<const float4*>(
      qkv_w + (size_t)d * W3 + DIM + h * HD);
  float acc = 0.f;
#pragma unroll 8
  for (int e4 = 0; e4 < 32; ++e4) {
    float4 w = w4[e4];
    acc += qs[e4*4+0]*w.x + qs[e4*4+1]*w.y + qs[e4*4+2]*w.z + qs[e4*4+3]*w.w;
  }
  float r = acc * SCALE;
  int i = h * DIM + d;
  short* rb = (short*)(ws + RB_OFF);
  rb[i] = bf_hi(r);
  rb[NH * DIM + i] = bf_hi(r - bf_hif(r));
  float g = (cls[d] + pos[d]) * r;
  for (int m = 1; m < 64; m <<= 1) g += __shfl_xor(g, m, 64);
  if ((threadIdx.x & 63) == 0) atomicAdd(&ws[G_OFF + h], g);
}

// K3: scores via MFMA, LDS-staged coalesced tok tile (verbatim R16).
// grid (8 jt, 16 b, 16 dc), 256 thr.
__global__ __launch_bounds__(256) void k3_scores_mfma(
    const float* __restrict__ x, const float* __restrict__ pos,
    float* __restrict__ ws) {
  int jt = blockIdx.x, b = blockIdx.y, dc = blockIdx.z;
  int t = threadIdx.x;
  __shared__ __attribute__((aligned(16))) short ths[64][136];
  __shared__ __attribute__((aligned(16))) short tls[64][136];
  const size_t xb = (size_t)b * CC * DD * 256;
#pragma unroll
  for (int i = 0; i < 8; ++i) {
    int idx = i * 256 + t;                // 0..2047
    int r = idx >> 5;                     // row 0..63
    int c4 = idx & 31;                    // float4 within row
    int jr = 1 + jt * 64 + r;
    if (jr > 511) jr = 511;               // clamp (dup row, masked at store)
    int d = dc * 128 + c4 * 4;
    int cc = d >> 8, doff = d & 255;
    float4 xv = *reinterpret_cast<const float4*>(
        x + xb + (size_t)cc * DD * 256 + (size_t)(jr - 1) * 256 + doff);
    float4 pv = *reinterpret_cast<const float4*>(pos + (size_t)jr * DIM + d);
    float f[4] = {xv.x + pv.x, xv.y + pv.y, xv.z + pv.z, xv.w + pv.w};
#pragma unroll
    for (int k = 0; k < 4; ++k) {
      ths[r][c4 * 4 + k] = bf_hi(f[k]);
      tls[r][c4 * 4 + k] = bf_hi(f[k] - bf_hif(f[k]));
    }
  }
  __syncthreads();
  int w = t >> 6, l = t & 63;
  int m16 = l & 15, kg = l >> 4;
  const short* rh = (const short*)(ws + RB_OFF);
  const short* rl = rh + NH * DIM;
  floatx4 acc = {0.f, 0.f, 0.f, 0.f};
#pragma unroll
  for (int kk = 0; kk < 4; ++kk) {
    int dl = kk * 32 + kg * 8;            // local d 0..127
    int gd = dc * 128 + dl;               // global d
    short8 ahi = *reinterpret_cast<const short8*>(&ths[w * 16 + m16][dl]);
    short8 alo = *reinterpret_cast<const short8*>(&tls[w * 16 + m16][dl]);
    short8 bhi = *reinterpret_cast<const short8*>(rh + m16 * DIM + gd);
    short8 blo = *reinterpret_cast<const short8*>(rl + m16 * DIM + gd);
    acc = __builtin_amdgcn_mfma_f32_16x16x32_bf16(ahi, bhi, acc, 0, 0, 0);
    acc = __builtin_amdgcn_mfma_f32_16x16x32_bf16(ahi, blo, acc, 0, 0, 0);
    acc = __builtin_amdgcn_mfma_f32_16x16x32_bf16(alo, bhi, acc, 0, 0, 0);
  }
  // C layout: col(h) = l&15, row(j) = kg*4 + reg  [m89-verified]
  int h = m16;
#pragma unroll
  for (int reg = 0; reg < 4; ++reg) {
    int j = 1 + jt * 64 + w * 16 + kg * 4 + reg;
    if (j < SEQ)
      ws[SCP_OFF + (size_t)dc * SCPSZ + (size_t)(b * NH + h) * SEQ + j] =
          acc[reg];
  }
}

// K4: softmax per (b,h): sum 16 score partials + gamma -> p bf16 hi/lo
// (verbatim R16). grid (16 h, 16 b) x 64.
__global__ __launch_bounds__(64) void k4_softmax(float* __restrict__ ws) {
  int h = blockIdx.x, b = blockIdx.y, l = threadIdx.x;
  const float* sc0 = ws + SCP_OFF + (size_t)(b * NH + h) * SEQ;
  float gam = ws[G_OFF + h];
  float s[8];
#pragma unroll
  for (int i = 0; i < 8; ++i) {
    int j = i * 64 + l;
    float a = 0.f;
#pragma unroll
    for (int p = 0; p < 16; ++p) a += sc0[(size_t)p * SCPSZ + j];
    s[i] = a;
  }
  if (l == 0) s[0] = gam;                 // j=0 slot holds the cls score
  float mx = s[0];
#pragma unroll
  for (int i = 1; i < 8; ++i) mx = fmaxf(mx, s[i]);
  for (int m = 1; m < 64; m <<= 1) mx = fmaxf(mx, __shfl_xor(mx, m, 64));
  float e[8], sum = 0.f;
#pragma unroll
  for (int i = 0; i < 8; ++i) { e[i] = __expf(s[i] - mx); sum += e[i]; }
  for (int m = 1; m < 64; m <<= 1) sum += __shfl_xor(sum, m, 64);
  float inv = 1.f / sum;
  short* ph = (short*)(ws + PB_OFF);
  short* pl = ph + NH * SEQ * BB;
#pragma unroll
  for (int i = 0; i < 8; ++i) {
    float p = e[i] * inv;
    int j = i * 64 + l;
    ph[(size_t)(b * NH + h) * SEQ + j] = bf_hi(p);
    pl[(size_t)(b * NH + h) * SEQ + j] = bf_hi(p - bf_hif(p));
  }
}

// K5: u-partial[js][b] = p[:, js-half] @ tok[js-half] via MFMA. 2-way j
// split: 8 barriers/block, 4 blocks/CU (p-LDS halved). PV core otherwise
// verbatim R16. grid (32 dt, 16 b, 2 js), 256 thr.
__global__ __launch_bounds__(256) void k5_pv_mfma(
    const float* __restrict__ x, const float* __restrict__ pos,
    const float* __restrict__ cls, float* __restrict__ ws) {
  int dt = blockIdx.x, b = blockIdx.y, js = blockIdx.z, t = threadIdx.x;
  __shared__ __attribute__((aligned(16))) short phl[NH * PSTR];
  __shared__ __attribute__((aligned(16))) short pll[NH * PSTR];
  __shared__ short ths[2][CJ][TSTR];
  __shared__ short tls[2][CJ][TSTR];
  int w = t >> 6, l = t & 63;
  int j0 = js * 256;                      // this block's j-half base
  // ---- p staging from PB (this half only) ----
  const short* phg = (const short*)(ws + PB_OFF);
  const short* plg = phg + NH * SEQ * BB;
  for (int s = t; s < NH * 128; s += 256) {
    int h = s >> 7, j2 = (s & 127) * 2;
    *reinterpret_cast<int*>(&phl[h * PSTR + j2]) =
        *reinterpret_cast<const int*>(
            &phg[(size_t)(b * NH + h) * SEQ + j0 + j2]);
    *reinterpret_cast<int*>(&pll[h * PSTR + j2]) =
        *reinterpret_cast<const int*>(
            &plg[(size_t)(b * NH + h) * SEQ + j0 + j2]);
  }
  // ---- tok staging: 32j x 64d chunk, coalesced float4, bf16 hi/lo ----
  const size_t xb = (size_t)b * CC * DD * 256;
  auto stage = [&](int kk, int buf) {
#pragma unroll
    for (int rep = 0; rep < 2; ++rep) {
      int idx = rep * 256 + t;
      int jj = idx >> 4, f4 = idx & 15;   // 32 rows x 16 float4
      int j = j0 + kk * CJ + jj;
      int dbase = dt * 64 + f4 * 4;
      float4 pv = *reinterpret_cast<const float4*>(pos + (size_t)j * DIM + dbase);
      float4 xv;
      if (j == 0) {
        xv = *reinterpret_cast<const float4*>(cls + dbase);
      } else {
        int c = dbase >> 8, doff = dbase & 255;
        xv = *reinterpret_cast<const float4*>(
            x + xb + (size_t)c * DD * 256 + (size_t)(j - 1) * 256 + doff);
      }
      float f[4] = {xv.x + pv.x, xv.y + pv.y, xv.z + pv.z, xv.w + pv.w};
#pragma unroll
      for (int k = 0; k < 4; ++k) {
        ths[buf][jj][f4 * 4 + k] = bf_hi(f[k]);
        tls[buf][jj][f4 * 4 + k] = bf_hi(f[k] - bf_hif(f[k]));
      }
    }
  };
  stage(0, 0);
  // ---- MFMA main loop (double-buffered over 8 j-chunks of this half) ----
  int m16 = l & 15, kq = l >> 4;
  int wd = w * 16 + m16;
  int dcol = dt * 64 + wd;
  const short8* pph = reinterpret_cast<const short8*>(&phl[m16 * PSTR]);
  const short8* ppl = reinterpret_cast<const short8*>(&pll[m16 * PSTR]);
  floatx4 acc = {0.f, 0.f, 0.f, 0.f};
  for (int kk = 0; kk < 8; ++kk) {
    __syncthreads();
    if (kk < 7) stage(kk + 1, (kk + 1) & 1);
    int buf = kk & 1;
    short8 thi, tlo;
#pragma unroll
    for (int i = 0; i < 8; ++i) {
      thi[i] = ths[buf][kq * 8 + i][wd];
      tlo[i] = tls[buf][kq * 8 + i][wd];
    }
    short8 phi = pph[kk * 4 + kq];
    short8 plo = ppl[kk * 4 + kq];
    acc = __builtin_amdgcn_mfma_f32_16x16x32_bf16(phi, thi, acc, 0, 0, 0);
    acc = __builtin_amdgcn_mfma_f32_16x16x32_bf16(phi, tlo, acc, 0, 0, 0);
    acc = __builtin_amdgcn_mfma_f32_16x16x32_bf16(plo, thi, acc, 0, 0, 0);
  }
  // C: col(d) = l&15, row(h) = kq*4+reg
  float* ub = ws + U_OFF + (size_t)js * USZ + (size_t)b * NH * DIM + dcol;
#pragma unroll
  for (int reg = 0; reg < 4; ++reg)
    ub[(size_t)(kq * 4 + reg) * DIM] = acc[reg];
}

// K6: ao[b][m] += u-chunk . Wv; u staged by summing the 2 js-partials.
// grid (8 nt, 64 dc).
__global__ __launch_bounds__(256) void k6_ao(
    const float* __restrict__ qkv_w, const float* __restrict__ qkv_b,
    float* __restrict__ ws) {
  int nt = blockIdx.x, dc = blockIdx.y, t = threadIdx.x;
  int m = nt * 256 + t;
  int h0 = nt * 2;
  int d0 = dc * 32;
  __shared__ float us[2][32][20];
  for (int i = t; i < 2 * 32 * BB; i += 256) {
    int dd = i & 31, b = (i >> 5) & 15, hh = i >> 9;
    size_t idx = U_OFF + (size_t)(b * NH + h0 + hh) * DIM + d0 + dd;
    us[hh][dd][b] = ws[idx] + ws[idx + USZ];
  }
  __syncthreads();
  int hl = t >> 7;
  float acc[BB];
#pragma unroll
  for (int b = 0; b < BB; ++b) acc[b] = 0.f;
  const float* wcol = qkv_w + (size_t)d0 * W3 + 2 * DIM + m;
#pragma unroll 4
  for (int dd = 0; dd < 32; ++dd) {
    float w = wcol[(size_t)dd * W3];
    const float4* u4 = reinterpret_cast<const float4*>(&us[hl][dd][0]);
    float4 u0 = u4[0], u1 = u4[1], u2 = u4[2], u3 = u4[3];
    acc[0]  += u0.x * w; acc[1]  += u0.y * w; acc[2]  += u0.z * w; acc[3]  += u0.w * w;
    acc[4]  += u1.x * w; acc[5]  += u1.y * w; acc[6]  += u1.z * w; acc[7]  += u1.w * w;
    acc[8]  += u2.x * w; acc[9]  += u2.y * w; acc[10] += u2.z * w; acc[11] += u2.w * w;
    acc[12] += u3.x * w; acc[13] += u3.y * w; acc[14] += u3.z * w; acc[15] += u3.w * w;
  }
  float bias = (dc == 0) ? qkv_b[2 * DIM + m] : 0.f;
#pragma unroll
  for (int b = 0; b < BB; ++b)
    atomicAdd(&ws[AO_OFF + b * DIM + m], acc[b] + bias);
}

// K7: out[b][n] += ao-chunk . proj_w (verbatim R16). grid (8 nt, 64 mc).
__global__ __launch_bounds__(256) void k7_out(
    const float* __restrict__ proj_w, const float* __restrict__ proj_b,
    const float* __restrict__ ws, float* __restrict__ out) {
  int nt = blockIdx.x, mc = blockIdx.y, t = threadIdx.x;
  int n = nt * 256 + t;
  int m0 = mc * 32;
  __shared__ float as[32][20];
  for (int i = t; i < 32 * BB; i += 256) {
    int mm = i & 31, b = i >> 5;
    as[mm][b] = ws[AO_OFF + b * DIM + m0 + mm];
  }
  __syncthreads();
  float acc[BB];
#pragma unroll
  for (int b = 0; b < BB; ++b) acc[b] = 0.f;
  const float* wcol = proj_w + (size_t)m0 * DIM + n;
#pragma unroll 4
  for (int mm = 0; mm < 32; ++mm) {
    float w = wcol[(size_t)mm * DIM];
    const float4* a4 = reinterpret_cast<const float4*>(&as[mm][0]);
    float4 a0 = a4[0], a1 = a4[1], a2 = a4[2], a3 = a4[3];
    acc[0]  += a0.x * w; acc[1]  += a0.y * w; acc[2]  += a0.z * w; acc[3]  += a0.w * w;
    acc[4]  += a1.x * w; acc[5]  += a1.y * w; acc[6]  += a1.z * w; acc[7]  += a1.w * w;
    acc[8]  += a2.x * w; acc[9]  += a2.y * w; acc[10] += a2.z * w; acc[11] += a2.w * w;
    acc[12] += a3.x * w; acc[13] += a3.y * w; acc[14] += a3.z * w; acc[15] += a3.w * w;
  }
  float bias = (mc == 0) ? proj_b[n] : 0.f;
#pragma unroll
  for (int b = 0; b < BB; ++b)
    atomicAdd(&out[b * DIM + n], acc[b] + bias);
}

extern "C" void kernel_launch(void* const* d_in, const int* in_sizes, int n_in,
                              void* d_out, int out_size, void* d_ws, size_t ws_size,
                              hipStream_t stream) {
  const float* x      = (const float*)d_in[0];
  const float* pos    = (const float*)d_in[1];
  const float* cls    = (const float*)d_in[2];
  const float* qkv_w  = (const float*)d_in[3];
  const float* qkv_b  = (const float*)d_in[4];
  const float* proj_w = (const float*)d_in[5];
  const float* proj_b = (const float*)d_in[6];
  float* ws  = (float*)d_ws;
  float* out = (float*)d_out;

  k1_q          <<<dim3(8, 64),     256, 0, stream>>>(pos, cls, qkv_w, qkv_b, ws, out);
  k2_r          <<<dim3(16, 16),    128, 0, stream>>>(qkv_w, pos, cls, ws);
  k3_scores_mfma<<<dim3(8, 16, 16), 256, 0, stream>>>(x, pos, ws);
  k4_softmax    <<<dim3(16, 16),     64, 0, stream>>>(ws);
  k5_pv_mfma    <<<dim3(32, 16, 2), 256, 0, stream>>>(x, pos, cls, ws);
  k6_ao         <<<dim3(8, 64),     256, 0, stream>>>(qkv_w, qkv_b, ws);
  k7_out        <<<dim3(8, 64),     256, 0, stream>>>(proj_w, proj_b, ws, out);
}